// Round 1
// baseline (1319.806 us; speedup 1.0000x reference)
//
#include <hip/hip_runtime.h>

// Varlen non-causal attention, qkv-packed (T,3,H,D) fp32, flash-style online softmax.
// Block = 256 threads, tile = 64 queries x 64 keys, one head per block.
// LDS: Qt (Q transposed, persistent), KV (K^T during scores, then V row-major),
// St (P transposed between phases). Stride 68 keeps 16B alignment + kills conflicts.

#define TQ 64
#define TK 64
#define DH 64
#define HEADS 8
#define STR 68
#define NEG_INF -1e9f

__global__ __launch_bounds__(256, 2)
void favarlen_kernel(const float* __restrict__ qkv,
                     const int* __restrict__ cu, int n_cu, int T,
                     float* __restrict__ out) {
    __shared__ float Qt[DH][STR];   // Qt[d][r] = Q[r][d]
    __shared__ float KV[DH][STR];   // Kt[d][c] during scores; V[k][d] during PV
    __shared__ float St[TK][STR];   // St[k][r] = P[r][k]

    const int tid = threadIdx.x;
    const int h  = blockIdx.y;
    const int t0 = blockIdx.x * TQ;
    const int tx = tid & 15;        // -> key cols 4*tx..4*tx+3 / out dims 4*tx..
    const int ty = tid >> 4;        // -> query rows 4*ty..4*ty+3
    const int srow = tid >> 4;      // staging row
    const int sf4  = tid & 15;      // staging float4 column

    // per-row segment bounds (rows r = 4*ty + i)
    int lo[4], hi[4];
    #pragma unroll
    for (int i = 0; i < 4; ++i) {
        int t = t0 + 4 * ty + i;
        if (t > T - 1) t = T - 1;
        int s = 0;
        for (int j = 1; j < n_cu - 1; ++j) if (cu[j] <= t) s = j;
        lo[i] = cu[s];
        hi[i] = cu[s + 1];
    }
    // block-wide key range: first row's segment start .. last row's segment end
    int kb, ke;
    {
        int s = 0;
        for (int j = 1; j < n_cu - 1; ++j) if (cu[j] <= t0) s = j;
        kb = cu[s];
        int tl = t0 + TQ - 1; if (tl > T - 1) tl = T - 1;
        s = 0;
        for (int j = 1; j < n_cu - 1; ++j) if (cu[j] <= tl) s = j;
        ke = cu[s + 1];
    }

    // ---- stage Q (transposed) ----
    #pragma unroll
    for (int rr = 0; rr < TQ; rr += 16) {
        int r = rr + srow;
        int t = t0 + r;
        float4 v = make_float4(0.f, 0.f, 0.f, 0.f);
        if (t < T)
            v = *(const float4*)(qkv + (((size_t)t * 3 + 0) * HEADS + h) * DH + 4 * sf4);
        Qt[4*sf4+0][r] = v.x; Qt[4*sf4+1][r] = v.y;
        Qt[4*sf4+2][r] = v.z; Qt[4*sf4+3][r] = v.w;
    }

    float m_[4], l_[4], acc[4][4];
    #pragma unroll
    for (int i = 0; i < 4; ++i) {
        m_[i] = NEG_INF; l_[i] = 0.f;
        #pragma unroll
        for (int j = 0; j < 4; ++j) acc[i][j] = 0.f;
    }
    __syncthreads();

    const float scale = 0.125f;  // 1/sqrt(64)
    const int c0_start = (kb / TK) * TK;

    for (int c0 = c0_start; c0 < ke; c0 += TK) {
        // ---- stage K^T into KV ----
        #pragma unroll
        for (int rr = 0; rr < TK; rr += 16) {
            int krow = rr + srow;
            int kk = c0 + krow;
            float4 v = make_float4(0.f, 0.f, 0.f, 0.f);
            if (kk < T)
                v = *(const float4*)(qkv + (((size_t)kk * 3 + 1) * HEADS + h) * DH + 4 * sf4);
            KV[4*sf4+0][krow] = v.x; KV[4*sf4+1][krow] = v.y;
            KV[4*sf4+2][krow] = v.z; KV[4*sf4+3][krow] = v.w;
        }
        __syncthreads();

        // ---- scores: s[i][j] = Q[4ty+i] . K[4tx+j] ----
        float s[4][4];
        #pragma unroll
        for (int i = 0; i < 4; ++i)
            #pragma unroll
            for (int j = 0; j < 4; ++j) s[i][j] = 0.f;

        #pragma unroll
        for (int d4 = 0; d4 < DH; d4 += 4) {
            float qa[4][4], ka[4][4];
            #pragma unroll
            for (int m = 0; m < 4; ++m) {
                float4 q4 = *(const float4*)&Qt[d4 + m][4 * ty];
                float4 k4 = *(const float4*)&KV[d4 + m][4 * tx];
                qa[m][0] = q4.x; qa[m][1] = q4.y; qa[m][2] = q4.z; qa[m][3] = q4.w;
                ka[m][0] = k4.x; ka[m][1] = k4.y; ka[m][2] = k4.z; ka[m][3] = k4.w;
            }
            #pragma unroll
            for (int m = 0; m < 4; ++m)
                #pragma unroll
                for (int i = 0; i < 4; ++i)
                    #pragma unroll
                    for (int j = 0; j < 4; ++j)
                        s[i][j] = fmaf(qa[m][i], ka[m][j], s[i][j]);
        }

        // ---- mask + online softmax (rows live across 16-lane tx groups) ----
        #pragma unroll
        for (int i = 0; i < 4; ++i) {
            float rm = NEG_INF;
            #pragma unroll
            for (int j = 0; j < 4; ++j) {
                int kg = c0 + 4 * tx + j;
                bool valid = (kg >= lo[i]) && (kg < hi[i]);
                s[i][j] = valid ? s[i][j] * scale : NEG_INF;
                rm = fmaxf(rm, s[i][j]);
            }
            #pragma unroll
            for (int off = 1; off <= 8; off <<= 1)
                rm = fmaxf(rm, __shfl_xor(rm, off));
            float mn = fmaxf(m_[i], rm);
            float al = __expf(m_[i] - mn);   // exp(0)=1 when both -inf
            float rs = 0.f;
            #pragma unroll
            for (int j = 0; j < 4; ++j) {
                float p = (s[i][j] > 0.5f * NEG_INF) ? __expf(s[i][j] - mn) : 0.f;
                s[i][j] = p;
                rs += p;
            }
            #pragma unroll
            for (int off = 1; off <= 8; off <<= 1)
                rs += __shfl_xor(rs, off);
            l_[i] = l_[i] * al + rs;
            m_[i] = mn;
            #pragma unroll
            for (int j = 0; j < 4; ++j) acc[i][j] *= al;
        }

        // ---- write P^T to St ----
        #pragma unroll
        for (int j = 0; j < 4; ++j) {
            float4 pj = make_float4(s[0][j], s[1][j], s[2][j], s[3][j]);
            *(float4*)&St[4 * tx + j][4 * ty] = pj;
        }
        __syncthreads();   // all waves done reading K; St visible

        // ---- stage V (row-major) over KV ----
        #pragma unroll
        for (int rr = 0; rr < TK; rr += 16) {
            int krow = rr + srow;
            int kk = c0 + krow;
            float4 v = make_float4(0.f, 0.f, 0.f, 0.f);
            if (kk < T)
                v = *(const float4*)(qkv + (((size_t)kk * 3 + 2) * HEADS + h) * DH + 4 * sf4);
            *(float4*)&KV[krow][4 * sf4] = v;
        }
        __syncthreads();

        // ---- PV: acc[i][j] += P[4ty+i][k] * V[k][4tx+j] ----
        #pragma unroll
        for (int k4 = 0; k4 < TK; k4 += 4) {
            float sa[4][4], va[4][4];
            #pragma unroll
            for (int m = 0; m < 4; ++m) {
                float4 s4 = *(const float4*)&St[k4 + m][4 * ty];
                float4 v4 = *(const float4*)&KV[k4 + m][4 * tx];
                sa[m][0] = s4.x; sa[m][1] = s4.y; sa[m][2] = s4.z; sa[m][3] = s4.w;
                va[m][0] = v4.x; va[m][1] = v4.y; va[m][2] = v4.z; va[m][3] = v4.w;
            }
            #pragma unroll
            for (int m = 0; m < 4; ++m)
                #pragma unroll
                for (int i = 0; i < 4; ++i)
                    #pragma unroll
                    for (int j = 0; j < 4; ++j)
                        acc[i][j] = fmaf(sa[m][i], va[m][j], acc[i][j]);
        }
        __syncthreads();   // before next chunk restages K over KV
    }

    // ---- epilogue ----
    #pragma unroll
    for (int i = 0; i < 4; ++i) {
        int t = t0 + 4 * ty + i;
        if (t < T) {
            float inv = 1.f / l_[i];
            float4 o = make_float4(acc[i][0] * inv, acc[i][1] * inv,
                                   acc[i][2] * inv, acc[i][3] * inv);
            *(float4*)(out + ((size_t)t * HEADS + h) * DH + 4 * tx) = o;
        }
    }
}

extern "C" void kernel_launch(void* const* d_in, const int* in_sizes, int n_in,
                              void* d_out, int out_size, void* d_ws, size_t ws_size,
                              hipStream_t stream) {
    const float* qkv = (const float*)d_in[0];
    const int* cu    = (const int*)d_in[1];
    const int n_cu   = in_sizes[1];
    const int T      = in_sizes[0] / (3 * HEADS * DH);
    float* out       = (float*)d_out;

    dim3 grid((T + TQ - 1) / TQ, HEADS);
    favarlen_kernel<<<grid, 256, 0, stream>>>(qkv, cu, n_cu, T, out);
}

// Round 2
// 137.220 us; speedup vs baseline: 9.6182x; 9.6182x over previous
//
#include <hip/hip_runtime.h>

// Varlen non-causal attention, qkv-packed (T,3,H,D) fp32 in/out.
// bf16 MFMA (16x16x32) flash-style online softmax.
// Block = 256 threads (4 waves); block tile = 64 q-rows x 1 head; 16 q-rows/wave.
// LDS (bf16, leading stride 72 elems = 144 B => conflict-free b128 frag reads):
//   Ksh[key][d]   row-major K chunk  (B-operand of QK^T)
//   Vt [d][key]   transposed V chunk (B-operand of PV)
//   Psh[q][key]   P round-trip C-layout -> A-layout (wave-private rows)

#define HEADS 8
#define DH 64
#define TQ 64
#define TK 64
#define KSTR 72
#define NEG_BIG -1e30f

using f32x4 = __attribute__((ext_vector_type(4))) float;
using s16x8 = __attribute__((ext_vector_type(8))) short;
using u16x4 = __attribute__((ext_vector_type(4))) unsigned short;

__device__ inline unsigned short bf16b(float x) {
    union { float f; unsigned u; } c; c.f = x;
    unsigned r = c.u + 0x7fffu + ((c.u >> 16) & 1u);   // round-to-nearest-even
    return (unsigned short)(r >> 16);
}

__global__ __launch_bounds__(256, 2)
void fa_mfma_kernel(const float* __restrict__ qkv, const int* __restrict__ cu,
                    int n_cu, int T, float* __restrict__ out) {
    __shared__ unsigned short Ksh[TK][KSTR];
    __shared__ unsigned short Vt[DH][KSTR];
    __shared__ unsigned short Psh[TQ][KSTR];

    const int tid  = threadIdx.x;
    const int h    = blockIdx.y;
    const int t0   = blockIdx.x * TQ;
    const int w    = tid >> 6;        // wave id 0..3
    const int lane = tid & 63;
    const int n15  = lane & 15;       // mfma m / n index
    const int quad = lane >> 4;       // mfma k-quad / C-row group
    const int c4   = tid & 15;        // staging float4 col
    const int r0   = tid >> 4;        // staging row

    // ---- segment bounds for this lane's 4 accumulator rows (reg 0..3) ----
    int lo[4], hi[4];
    #pragma unroll
    for (int reg = 0; reg < 4; ++reg) {
        int t = t0 + w * 16 + quad * 4 + reg;
        if (t > T - 1) t = T - 1;
        int s = 0;
        for (int j = 1; j < n_cu - 1; ++j) if (cu[j] <= t) s = j;
        lo[reg] = cu[s];
        hi[reg] = cu[s + 1];
    }
    // ---- block-wide key range ----
    int kb, ke;
    {
        int s = 0;
        for (int j = 1; j < n_cu - 1; ++j) if (cu[j] <= t0) s = j;
        kb = cu[s];
        int tl = t0 + TQ - 1; if (tl > T - 1) tl = T - 1;
        s = 0;
        for (int j = 1; j < n_cu - 1; ++j) if (cu[j] <= tl) s = j;
        ke = cu[s + 1];
    }

    // ---- Q fragments (A-operand) held in registers: lane(m=n15, quad) ----
    s16x8 qfrag[2];
    {
        int tq = t0 + w * 16 + n15;
        int tc = tq < T ? tq : T - 1;
        const float* qp = qkv + (((size_t)tc * 3 + 0) * HEADS + h) * DH + quad * 8;
        #pragma unroll
        for (int kh = 0; kh < 2; ++kh) {
            float4 x = *(const float4*)(qp + kh * 32);
            float4 y = *(const float4*)(qp + kh * 32 + 4);
            s16x8 f;
            f[0] = (short)bf16b(x.x); f[1] = (short)bf16b(x.y);
            f[2] = (short)bf16b(x.z); f[3] = (short)bf16b(x.w);
            f[4] = (short)bf16b(y.x); f[5] = (short)bf16b(y.y);
            f[6] = (short)bf16b(y.z); f[7] = (short)bf16b(y.w);
            qfrag[kh] = f;
        }
    }

    f32x4 oacc[4];
    float m_[4], l_[4];
    #pragma unroll
    for (int i = 0; i < 4; ++i) {
        oacc[i] = (f32x4){0.f, 0.f, 0.f, 0.f};
        m_[i] = NEG_BIG; l_[i] = 0.f;
    }

    const float scale = 0.125f;  // 1/sqrt(64)
    const int c0_start = (kb / TK) * TK;

    for (int c0 = c0_start; c0 < ke; c0 += TK) {
        // ---- stage K chunk (row-major bf16) ----
        #pragma unroll
        for (int rr = 0; rr < TK; rr += 16) {
            int krow = rr + r0;
            int kk = c0 + krow;
            float4 v = make_float4(0.f, 0.f, 0.f, 0.f);
            if (kk >= 0 && kk < T)
                v = *(const float4*)(qkv + (((size_t)kk * 3 + 1) * HEADS + h) * DH + 4 * c4);
            u16x4 p; p[0] = bf16b(v.x); p[1] = bf16b(v.y); p[2] = bf16b(v.z); p[3] = bf16b(v.w);
            *(u16x4*)&Ksh[krow][4 * c4] = p;
        }
        // ---- stage V chunk transposed (Vt[d][key]), packed pair writes ----
        #pragma unroll
        for (int it = 0; it < 2; ++it) {
            int r2 = 2 * (r0 + 16 * it);        // even local key 0..62
            int ka = c0 + r2;
            float4 va = make_float4(0.f, 0.f, 0.f, 0.f);
            float4 vb = make_float4(0.f, 0.f, 0.f, 0.f);
            if (ka >= 0 && ka < T)
                va = *(const float4*)(qkv + (((size_t)ka * 3 + 2) * HEADS + h) * DH + 4 * c4);
            if (ka + 1 >= 0 && ka + 1 < T)
                vb = *(const float4*)(qkv + (((size_t)(ka + 1) * 3 + 2) * HEADS + h) * DH + 4 * c4);
            const float* pa = &va.x; const float* pb = &vb.x;
            #pragma unroll
            for (int i = 0; i < 4; ++i) {
                unsigned pk = (unsigned)bf16b(pa[i]) | ((unsigned)bf16b(pb[i]) << 16);
                *(unsigned*)&Vt[4 * c4 + i][r2] = pk;
            }
        }
        __syncthreads();

        // ---- scores: S = Q K^T  (D[q][key], C-layout) ----
        f32x4 sacc[4];
        #pragma unroll
        for (int nt = 0; nt < 4; ++nt) sacc[nt] = (f32x4){0.f, 0.f, 0.f, 0.f};
        #pragma unroll
        for (int nt = 0; nt < 4; ++nt) {
            #pragma unroll
            for (int kh = 0; kh < 2; ++kh) {
                s16x8 bfr = *(const s16x8*)&Ksh[nt * 16 + n15][kh * 32 + quad * 8];
                sacc[nt] = __builtin_amdgcn_mfma_f32_16x16x32_bf16(qfrag[kh], bfr, sacc[nt], 0, 0, 0);
            }
        }

        // ---- online softmax (per lane: 4 rows = quad*4+reg; 16 lanes/row) ----
        #pragma unroll
        for (int reg = 0; reg < 4; ++reg) {
            float sv[4];
            float rm = NEG_BIG;
            #pragma unroll
            for (int nt = 0; nt < 4; ++nt) {
                int key = c0 + nt * 16 + n15;
                bool valid = (key >= lo[reg]) && (key < hi[reg]);
                float s = valid ? sacc[nt][reg] * scale : NEG_BIG;
                sv[nt] = s;
                rm = fmaxf(rm, s);
            }
            #pragma unroll
            for (int off = 1; off <= 8; off <<= 1)
                rm = fmaxf(rm, __shfl_xor(rm, off));
            float mn = fmaxf(m_[reg], rm);
            float al = __expf(m_[reg] - mn);
            float rs = 0.f;
            int prow = w * 16 + quad * 4 + reg;
            #pragma unroll
            for (int nt = 0; nt < 4; ++nt) {
                float p = (sv[nt] > -1e29f) ? __expf(sv[nt] - mn) : 0.f;
                rs += p;
                Psh[prow][nt * 16 + n15] = bf16b(p);
            }
            #pragma unroll
            for (int off = 1; off <= 8; off <<= 1)
                rs += __shfl_xor(rs, off);
            l_[reg] = l_[reg] * al + rs;
            m_[reg] = mn;
            oacc[0][reg] *= al; oacc[1][reg] *= al;
            oacc[2][reg] *= al; oacc[3][reg] *= al;
        }

        // ---- PV: O += P V  (A from Psh wave-private rows, B from Vt) ----
        s16x8 afr[2];
        #pragma unroll
        for (int kh = 0; kh < 2; ++kh)
            afr[kh] = *(const s16x8*)&Psh[w * 16 + n15][kh * 32 + quad * 8];
        #pragma unroll
        for (int nt = 0; nt < 4; ++nt) {
            #pragma unroll
            for (int kh = 0; kh < 2; ++kh) {
                s16x8 bfr = *(const s16x8*)&Vt[nt * 16 + n15][kh * 32 + quad * 8];
                oacc[nt] = __builtin_amdgcn_mfma_f32_16x16x32_bf16(afr[kh], bfr, oacc[nt], 0, 0, 0);
            }
        }
        __syncthreads();   // Ksh/Vt reads done before next restage
    }

    // ---- epilogue: O /= l, store fp32 ----
    #pragma unroll
    for (int reg = 0; reg < 4; ++reg) {
        int t = t0 + w * 16 + quad * 4 + reg;
        if (t < T) {
            float inv = 1.f / fmaxf(l_[reg], 1e-30f);
            #pragma unroll
            for (int nt = 0; nt < 4; ++nt)
                out[((size_t)t * HEADS + h) * DH + nt * 16 + n15] = oacc[nt][reg] * inv;
        }
    }
}

extern "C" void kernel_launch(void* const* d_in, const int* in_sizes, int n_in,
                              void* d_out, int out_size, void* d_ws, size_t ws_size,
                              hipStream_t stream) {
    const float* qkv = (const float*)d_in[0];
    const int* cu    = (const int*)d_in[1];
    const int n_cu   = in_sizes[1];
    const int T      = in_sizes[0] / (3 * HEADS * DH);
    float* out       = (float*)d_out;

    dim3 grid((T + TQ - 1) / TQ, HEADS);
    fa_mfma_kernel<<<grid, 256, 0, stream>>>(qkv, cu, n_cu, T, out);
}

// Round 3
// 114.281 us; speedup vs baseline: 11.5488x; 1.2007x over previous
//
#include <hip/hip_runtime.h>

// Varlen non-causal attention, qkv-packed (T,3,H,D) fp32 in/out.
// bf16 MFMA (16x16x32) flash-style online softmax, split-K x2 with
// workspace partials + combine kernel.
//
// Main kernel: block = 256 thr (4 waves); tile = 64 q-rows x 1 head x 1 split.
// S^T trick: scores computed as K·Q^T so softmax rows live on lane&15 ->
//   2-shfl row reductions, scalar lo/hi, contiguous-key P writes (b64).
// LDS bf16, leading stride 72 (conflict-free b128 fragment reads).

#define HEADS 8
#define DH 64
#define TQ 64
#define TK 64
#define KSTR 72
#define NEG_BIG -1e30f
#define L2E 1.44269504088896340736f

using f32x4 = __attribute__((ext_vector_type(4))) float;
using s16x8 = __attribute__((ext_vector_type(8))) short;
using u16x4 = __attribute__((ext_vector_type(4))) unsigned short;

__device__ inline unsigned short bf16b(float x) {
    union { float f; unsigned u; } c; c.f = x;
    unsigned r = c.u + 0x7fffu + ((c.u >> 16) & 1u);   // RNE
    return (unsigned short)(r >> 16);
}
__device__ inline unsigned pk2(float a, float b) {
    return (unsigned)bf16b(a) | ((unsigned)bf16b(b) << 16);
}

__global__ __launch_bounds__(256, 4)
void fa_mfma_kernel(const float* __restrict__ qkv, const int* __restrict__ cu,
                    int n_cu, int T, float* __restrict__ out,
                    float* __restrict__ Opart, float* __restrict__ Mp,
                    float* __restrict__ Lp) {
    __shared__ unsigned short Ksh[TK][KSTR];
    __shared__ unsigned short Vt[DH][KSTR];
    __shared__ unsigned short Psh[TQ][KSTR];

    const int tid   = threadIdx.x;
    const int h     = blockIdx.y;
    const int t0    = blockIdx.x * TQ;
    const int split = blockIdx.z;
    const int nsplit = gridDim.z;
    const int w    = tid >> 6;
    const int lane = tid & 63;
    const int n15  = lane & 15;
    const int quad = lane >> 4;
    const int c4   = tid & 15;
    const int r0   = tid >> 4;

    // ---- per-lane row segment bounds (row q = n15 within wave) ----
    int trow = t0 + w * 16 + n15;
    if (trow > T - 1) trow = T - 1;
    int lo, hi;
    {
        int s = 0;
        for (int j = 1; j < n_cu - 1; ++j) if (cu[j] <= trow) s = j;
        lo = cu[s]; hi = cu[s + 1];
    }
    // ---- block-wide key range ----
    int kb, ke;
    {
        int s = 0;
        for (int j = 1; j < n_cu - 1; ++j) if (cu[j] <= t0) s = j;
        kb = cu[s];
        int tl = t0 + TQ - 1; if (tl > T - 1) tl = T - 1;
        s = 0;
        for (int j = 1; j < n_cu - 1; ++j) if (cu[j] <= tl) s = j;
        ke = cu[s + 1];
    }

    // ---- Q fragments (B-operand of K·Q^T), scale 1/8 folded (exact) ----
    s16x8 qfrag[2];
    {
        int tq = t0 + w * 16 + n15;
        int tc = tq < T ? tq : T - 1;
        const float* qp = qkv + (((size_t)tc * 3 + 0) * HEADS + h) * DH + quad * 8;
        #pragma unroll
        for (int kh = 0; kh < 2; ++kh) {
            float4 x = *(const float4*)(qp + kh * 32);
            float4 y = *(const float4*)(qp + kh * 32 + 4);
            s16x8 f;
            f[0] = (short)bf16b(x.x * 0.125f); f[1] = (short)bf16b(x.y * 0.125f);
            f[2] = (short)bf16b(x.z * 0.125f); f[3] = (short)bf16b(x.w * 0.125f);
            f[4] = (short)bf16b(y.x * 0.125f); f[5] = (short)bf16b(y.y * 0.125f);
            f[6] = (short)bf16b(y.z * 0.125f); f[7] = (short)bf16b(y.w * 0.125f);
            qfrag[kh] = f;
        }
    }

    f32x4 oacc[4];
    #pragma unroll
    for (int i = 0; i < 4; ++i) oacc[i] = (f32x4){0.f, 0.f, 0.f, 0.f};
    float m_ = NEG_BIG, l_ = 0.f;

    const int c0_start = (kb / TK) * TK + split * TK;

    for (int c0 = c0_start; c0 < ke; c0 += nsplit * TK) {
        // ---- stage K chunk (row-major bf16) ----
        #pragma unroll
        for (int rr = 0; rr < TK; rr += 16) {
            int krow = rr + r0;
            int kk = c0 + krow;
            float4 v = make_float4(0.f, 0.f, 0.f, 0.f);
            if (kk < T)
                v = *(const float4*)(qkv + (((size_t)kk * 3 + 1) * HEADS + h) * DH + 4 * c4);
            u16x4 p; p[0] = bf16b(v.x); p[1] = bf16b(v.y); p[2] = bf16b(v.z); p[3] = bf16b(v.w);
            *(u16x4*)&Ksh[krow][4 * c4] = p;
        }
        // ---- stage V transposed (Vt[d][key]) ----
        #pragma unroll
        for (int it = 0; it < 2; ++it) {
            int r2 = 2 * (r0 + 16 * it);
            int ka = c0 + r2;
            float4 va = make_float4(0.f, 0.f, 0.f, 0.f);
            float4 vb = make_float4(0.f, 0.f, 0.f, 0.f);
            if (ka < T)
                va = *(const float4*)(qkv + (((size_t)ka * 3 + 2) * HEADS + h) * DH + 4 * c4);
            if (ka + 1 < T)
                vb = *(const float4*)(qkv + (((size_t)(ka + 1) * 3 + 2) * HEADS + h) * DH + 4 * c4);
            const float* pa = &va.x; const float* pb = &vb.x;
            #pragma unroll
            for (int i = 0; i < 4; ++i) {
                unsigned pk = (unsigned)bf16b(pa[i]) | ((unsigned)bf16b(pb[i]) << 16);
                *(unsigned*)&Vt[4 * c4 + i][r2] = pk;
            }
        }
        __syncthreads();

        // ---- S^T = K · Q^T : lane holds S[q=n15][key = nt*16 + quad*4 + reg] ----
        f32x4 sacc[4];
        #pragma unroll
        for (int nt = 0; nt < 4; ++nt) sacc[nt] = (f32x4){0.f, 0.f, 0.f, 0.f};
        #pragma unroll
        for (int nt = 0; nt < 4; ++nt) {
            #pragma unroll
            for (int kh = 0; kh < 2; ++kh) {
                s16x8 kfr = *(const s16x8*)&Ksh[nt * 16 + n15][kh * 32 + quad * 8];
                sacc[nt] = __builtin_amdgcn_mfma_f32_16x16x32_bf16(kfr, qfrag[kh], sacc[nt], 0, 0, 0);
            }
        }

        // ---- mask (skip if chunk fully inside segment) ----
        if (!(c0 >= lo && c0 + TK <= hi)) {
            #pragma unroll
            for (int nt = 0; nt < 4; ++nt)
                #pragma unroll
                for (int reg = 0; reg < 4; ++reg) {
                    int key = c0 + nt * 16 + quad * 4 + reg;
                    bool valid = (key >= lo) && (key < hi);
                    sacc[nt][reg] = valid ? sacc[nt][reg] : NEG_BIG;
                }
        }

        // ---- online softmax: row = n15, reduce over quad lanes ----
        float rm = NEG_BIG;
        #pragma unroll
        for (int nt = 0; nt < 4; ++nt)
            #pragma unroll
            for (int reg = 0; reg < 4; ++reg) rm = fmaxf(rm, sacc[nt][reg]);
        rm = fmaxf(rm, __shfl_xor(rm, 16));
        rm = fmaxf(rm, __shfl_xor(rm, 32));
        float mn = fmaxf(m_, rm);
        float alpha = exp2f((m_ - mn) * L2E);
        float mnl = mn * L2E;
        float rs = 0.f;
        #pragma unroll
        for (int nt = 0; nt < 4; ++nt) {
            float p0 = exp2f(fmaf(sacc[nt][0], L2E, -mnl));
            float p1 = exp2f(fmaf(sacc[nt][1], L2E, -mnl));
            float p2 = exp2f(fmaf(sacc[nt][2], L2E, -mnl));
            float p3 = exp2f(fmaf(sacc[nt][3], L2E, -mnl));
            rs += (p0 + p1) + (p2 + p3);
            *(uint2*)&Psh[w * 16 + n15][nt * 16 + quad * 4] =
                make_uint2(pk2(p0, p1), pk2(p2, p3));
        }
        rs += __shfl_xor(rs, 16);
        rs += __shfl_xor(rs, 32);
        l_ = fmaf(l_, alpha, rs);
        m_ = mn;
        // rescale O rows (rows = quad*4+reg in C-layout)
        #pragma unroll
        for (int reg = 0; reg < 4; ++reg) {
            float ar = __shfl(alpha, quad * 4 + reg);
            oacc[0][reg] *= ar; oacc[1][reg] *= ar;
            oacc[2][reg] *= ar; oacc[3][reg] *= ar;
        }

        // ---- PV: O += P V ----
        s16x8 afr[2];
        #pragma unroll
        for (int kh = 0; kh < 2; ++kh)
            afr[kh] = *(const s16x8*)&Psh[w * 16 + n15][kh * 32 + quad * 8];
        #pragma unroll
        for (int nt = 0; nt < 4; ++nt) {
            #pragma unroll
            for (int kh = 0; kh < 2; ++kh) {
                s16x8 vfr = *(const s16x8*)&Vt[nt * 16 + n15][kh * 32 + quad * 8];
                oacc[nt] = __builtin_amdgcn_mfma_f32_16x16x32_bf16(afr[kh], vfr, oacc[nt], 0, 0, 0);
            }
        }
        __syncthreads();
    }

    // ---- epilogue ----
    if (nsplit == 1) {
        #pragma unroll
        for (int reg = 0; reg < 4; ++reg) {
            float lr = __shfl(l_, quad * 4 + reg);
            float inv = 1.f / fmaxf(lr, 1e-30f);
            int t = t0 + w * 16 + quad * 4 + reg;
            if (t < T) {
                #pragma unroll
                for (int nt = 0; nt < 4; ++nt)
                    out[((size_t)t * HEADS + h) * DH + nt * 16 + n15] = oacc[nt][reg] * inv;
            }
        }
    } else {
        #pragma unroll
        for (int reg = 0; reg < 4; ++reg) {
            int t = t0 + w * 16 + quad * 4 + reg;
            if (t < T) {
                size_t base = (((size_t)split * T + t) * HEADS + h) * DH;
                #pragma unroll
                for (int nt = 0; nt < 4; ++nt)
                    Opart[base + nt * 16 + n15] = oacc[nt][reg];
            }
        }
        int tq = t0 + w * 16 + n15;
        if (quad == 0 && tq < T) {
            size_t mi = ((size_t)split * T + tq) * HEADS + h;
            Mp[mi] = m_; Lp[mi] = l_;
        }
    }
}

__global__ __launch_bounds__(256)
void fa_combine_kernel(const float* __restrict__ Opart, const float* __restrict__ Mp,
                       const float* __restrict__ Lp, float* __restrict__ out, int T) {
    int i4 = blockIdx.x * blockDim.x + threadIdx.x;
    int total = T * HEADS * (DH / 4);
    if (i4 >= total) return;
    int th = i4 / (DH / 4);
    int d4 = i4 - th * (DH / 4);
    size_t stride = (size_t)T * HEADS * DH;
    int mlstride = T * HEADS;
    float m0 = Mp[th], m1 = Mp[mlstride + th];
    float l0 = Lp[th], l1 = Lp[mlstride + th];
    float M = fmaxf(m0, m1);
    float w0 = exp2f((m0 - M) * L2E);
    float w1 = exp2f((m1 - M) * L2E);
    float L = fmaxf(fmaf(l0, w0, l1 * w1), 1e-30f);
    float inv = 1.f / L;
    size_t off = (size_t)th * DH + 4 * d4;
    float4 a = *(const float4*)&Opart[off];
    float4 b = *(const float4*)&Opart[stride + off];
    float4 o;
    o.x = fmaf(a.x, w0, b.x * w1) * inv;
    o.y = fmaf(a.y, w0, b.y * w1) * inv;
    o.z = fmaf(a.z, w0, b.z * w1) * inv;
    o.w = fmaf(a.w, w0, b.w * w1) * inv;
    *(float4*)&out[off] = o;
}

extern "C" void kernel_launch(void* const* d_in, const int* in_sizes, int n_in,
                              void* d_out, int out_size, void* d_ws, size_t ws_size,
                              hipStream_t stream) {
    const float* qkv = (const float*)d_in[0];
    const int* cu    = (const int*)d_in[1];
    const int n_cu   = in_sizes[1];
    const int T      = in_sizes[0] / (3 * HEADS * DH);
    float* out       = (float*)d_out;

    const int NSPLIT = 2;
    size_t need = (size_t)NSPLIT * T * HEADS * DH * sizeof(float)
                + 2 * (size_t)NSPLIT * T * HEADS * sizeof(float);

    if (ws_size >= need) {
        float* Opart = (float*)d_ws;
        float* Mpp   = Opart + (size_t)NSPLIT * T * HEADS * DH;
        float* Lpp   = Mpp + (size_t)NSPLIT * T * HEADS;
        dim3 grid(T / TQ, HEADS, NSPLIT);
        fa_mfma_kernel<<<grid, 256, 0, stream>>>(qkv, cu, n_cu, T, out, Opart, Mpp, Lpp);
        int total4 = T * HEADS * (DH / 4);
        fa_combine_kernel<<<(total4 + 255) / 256, 256, 0, stream>>>(Opart, Mpp, Lpp, out, T);
    } else {
        dim3 grid(T / TQ, HEADS, 1);
        fa_mfma_kernel<<<grid, 256, 0, stream>>>(qkv, cu, n_cu, T, out,
                                                 (float*)d_ws, (float*)d_ws, (float*)d_ws);
    }
}

// Round 4
// 105.946 us; speedup vs baseline: 12.4573x; 1.0787x over previous
//
#include <hip/hip_runtime.h>

// Varlen non-causal attention, qkv-packed (T,3,H,D) fp32 in/out.
// 3-kernel pipeline:
//  1) prep:   fp32 qkv -> bf16 Qb[t][h][d] (x0.125 folded), Kb[h][t][d], Vtb[h][d][t]
//  2) main:   bf16 MFMA flash attention, split-K x2; K/V staged via
//             global_load_lds(16B) with XOR-swizzled LDS layout (conflict-free
//             both for the DMA writes and the b128 fragment reads)
//  3) combine: merge split-K partials (m,l,O) -> out

#define HEADS 8
#define DH 64
#define TQ 64
#define TK 64
#define PSTR 72
#define NEG_BIG -1e30f
#define L2E 1.44269504088896340736f

using f32x4 = __attribute__((ext_vector_type(4))) float;
using s16x8 = __attribute__((ext_vector_type(8))) short;

__device__ inline unsigned short bf16b(float x) {
    union { float f; unsigned u; } c; c.f = x;
    unsigned r = c.u + 0x7fffu + ((c.u >> 16) & 1u);   // RNE
    return (unsigned short)(r >> 16);
}

#if __has_builtin(__builtin_amdgcn_cvt_pk_bf16_f32)
__device__ inline unsigned pk2(float a, float b) {
    auto v = __builtin_amdgcn_cvt_pk_bf16_f32(a, b);
    unsigned u; __builtin_memcpy(&u, &v, 4); return u;
}
#else
__device__ inline unsigned pk2(float a, float b) {
    return (unsigned)bf16b(a) | ((unsigned)bf16b(b) << 16);
}
#endif

// ---------------- pre-pass: convert + re-layout ----------------
__global__ __launch_bounds__(256)
void prep_kernel(const float* __restrict__ qkv, unsigned short* __restrict__ Qb,
                 unsigned short* __restrict__ Kb, unsigned short* __restrict__ Vtb,
                 int T) {
    __shared__ unsigned short Lt[64][PSTR];
    const int m = blockIdx.z, h = blockIdx.y, t0 = blockIdx.x * 64;
    const int tid = threadIdx.x, d8 = tid & 7, tr = tid >> 3;   // tr 0..31

    #pragma unroll
    for (int i = 0; i < 2; ++i) {
        int t = t0 + i * 32 + tr;
        int tc = t < T ? t : T - 1;
        const float* src = qkv + ((size_t)tc * 3 + m) * (HEADS * DH) + h * DH + d8 * 8;
        float4 a = *(const float4*)src;
        float4 b = *(const float4*)(src + 4);
        if (m == 0) {
            a.x *= 0.125f; a.y *= 0.125f; a.z *= 0.125f; a.w *= 0.125f;
            b.x *= 0.125f; b.y *= 0.125f; b.z *= 0.125f; b.w *= 0.125f;
        }
        unsigned p0 = pk2(a.x, a.y), p1 = pk2(a.z, a.w);
        unsigned p2 = pk2(b.x, b.y), p3 = pk2(b.z, b.w);
        if (m == 2) {
            *(uint2*)&Lt[i * 32 + tr][d8 * 8]     = make_uint2(p0, p1);
            *(uint2*)&Lt[i * 32 + tr][d8 * 8 + 4] = make_uint2(p2, p3);
        } else if (t < T) {
            unsigned short* dst = (m == 0)
                ? (Qb + (size_t)t * (HEADS * DH) + h * DH + d8 * 8)
                : (Kb + ((size_t)h * T + t) * DH + d8 * 8);
            *(uint4*)dst = make_uint4(p0, p1, p2, p3);
        }
    }
    if (m == 2) {
        __syncthreads();
        const int d = tid >> 2, tg = tid & 3;
        #pragma unroll
        for (int p = 0; p < 2; ++p) {
            int G = tg + 4 * p;
            int td = t0 + G * 8;
            unsigned u[4];
            #pragma unroll
            for (int jj = 0; jj < 4; ++jj)
                u[jj] = (unsigned)Lt[G * 8 + 2 * jj][d] |
                        ((unsigned)Lt[G * 8 + 2 * jj + 1][d] << 16);
            if (td < T)
                *(uint4*)(Vtb + ((size_t)h * DH + d) * T + td) =
                    make_uint4(u[0], u[1], u[2], u[3]);
        }
    }
}

// ---------------- main flash kernel ----------------
__global__ __launch_bounds__(256, 4)
void fa_main(const unsigned short* __restrict__ Qb, const unsigned short* __restrict__ Kb,
             const unsigned short* __restrict__ Vtb, const int* __restrict__ cu,
             int n_cu, int T, float* __restrict__ out,
             float* __restrict__ Opart, float* __restrict__ Mp, float* __restrict__ Lp) {
    __shared__ unsigned short Ksh[TK * DH];   // swizzled 16B granules: g = row*8 + (gd^(row&7))
    __shared__ unsigned short Vsh[DH * TK];   // same swizzle, rows = d, cols = keys
    __shared__ unsigned short Psh[TQ][PSTR];

    const int tid = threadIdx.x;
    const int h = blockIdx.y, t0 = blockIdx.x * TQ;
    const int split = blockIdx.z, nsplit = gridDim.z;
    const int w = tid >> 6, lane = tid & 63, n15 = lane & 15, quad = lane >> 4;

    // ---- segment bounds ----
    int trow = t0 + w * 16 + n15; if (trow > T - 1) trow = T - 1;
    int lo, hi;
    { int s = 0; for (int j = 1; j < n_cu - 1; ++j) if (cu[j] <= trow) s = j;
      lo = cu[s]; hi = cu[s + 1]; }
    int kb_, ke;
    { int s = 0; for (int j = 1; j < n_cu - 1; ++j) if (cu[j] <= t0) s = j;
      kb_ = cu[s];
      int tl = t0 + TQ - 1; if (tl > T - 1) tl = T - 1;
      s = 0; for (int j = 1; j < n_cu - 1; ++j) if (cu[j] <= tl) s = j;
      ke = cu[s + 1]; }

    // ---- Q fragments (bf16, pre-scaled) ----
    s16x8 qfrag[2];
    {
        int tc = t0 + w * 16 + n15; if (tc > T - 1) tc = T - 1;
        const unsigned short* qp = Qb + (size_t)tc * (HEADS * DH) + h * DH + quad * 8;
        qfrag[0] = *(const s16x8*)qp;
        qfrag[1] = *(const s16x8*)(qp + 32);
    }

    // ---- staging lane constants ----
    const unsigned short* kb_h = Kb + (size_t)h * T * DH;
    const unsigned short* vt_h = Vtb + (size_t)h * DH * T;
    int krow_rel[2], vkey_off[2];
    const unsigned short* kbase[2];
    const unsigned short* vbase[2];
    #pragma unroll
    for (int i = 0; i < 2; ++i) {
        int gg = i * 64 + lane;           // wave-local granule 0..127
        int rr = gg >> 3;                 // 0..15
        int gc = gg & 7;
        int row = w * 16 + rr;            // K row / V d-row (0..63)
        int gcol = gc ^ (row & 7);
        krow_rel[i] = row;
        kbase[i] = kb_h + gcol * 8;                 // + rk*64 per chunk
        vbase[i] = vt_h + (size_t)row * T;          // + key per chunk
        vkey_off[i] = gcol * 8;
    }
    // fragment read byte-offsets (valid for both Ksh and Vsh)
    int off16[2];
    #pragma unroll
    for (int kh = 0; kh < 2; ++kh)
        off16[kh] = n15 * 128 + (((kh * 4 + quad) ^ (n15 & 7)) * 16);

    f32x4 oacc[4];
    #pragma unroll
    for (int i = 0; i < 4; ++i) oacc[i] = (f32x4){0.f, 0.f, 0.f, 0.f};
    float m_ = NEG_BIG, l_ = 0.f;

    const int c0_start = (kb_ / TK) * TK + split * TK;
    for (int c0 = c0_start; c0 < ke; c0 += nsplit * TK) {
        // ---- async stage K + Vt (16B per lane, swizzled-linear LDS) ----
        #pragma unroll
        for (int i = 0; i < 2; ++i) {
            int rk = c0 + krow_rel[i]; if (rk > T - 1) rk = T - 1;
            __builtin_amdgcn_global_load_lds(
                (const __attribute__((address_space(1))) void*)(kbase[i] + ((size_t)rk << 6)),
                (__attribute__((address_space(3))) void*)&Ksh[(w * 128 + i * 64) * 8],
                16, 0, 0);
            int kv = c0 + vkey_off[i]; if (kv > T - 8) kv = T - 8;
            __builtin_amdgcn_global_load_lds(
                (const __attribute__((address_space(1))) void*)(vbase[i] + kv),
                (__attribute__((address_space(3))) void*)&Vsh[(w * 128 + i * 64) * 8],
                16, 0, 0);
        }
        __syncthreads();

        // ---- S^T = K·Q^T : lane holds S[q=n15][key = nt*16 + quad*4 + reg] ----
        const char* Kc = (const char*)Ksh;
        f32x4 sacc[4];
        #pragma unroll
        for (int nt = 0; nt < 4; ++nt) {
            s16x8 k0 = *(const s16x8*)(Kc + nt * 2048 + off16[0]);
            s16x8 k1 = *(const s16x8*)(Kc + nt * 2048 + off16[1]);
            f32x4 z = (f32x4){0.f, 0.f, 0.f, 0.f};
            z = __builtin_amdgcn_mfma_f32_16x16x32_bf16(k0, qfrag[0], z, 0, 0, 0);
            z = __builtin_amdgcn_mfma_f32_16x16x32_bf16(k1, qfrag[1], z, 0, 0, 0);
            sacc[nt] = z;
        }

        // ---- mask (only for boundary chunks) ----
        if (!(c0 >= lo && c0 + TK <= hi)) {
            #pragma unroll
            for (int nt = 0; nt < 4; ++nt)
                #pragma unroll
                for (int reg = 0; reg < 4; ++reg) {
                    int key = c0 + nt * 16 + quad * 4 + reg;
                    bool valid = (key >= lo) && (key < hi);
                    sacc[nt][reg] = valid ? sacc[nt][reg] : NEG_BIG;
                }
        }

        // ---- online softmax (row = n15; reduce across quad lanes) ----
        float rm = NEG_BIG;
        #pragma unroll
        for (int nt = 0; nt < 4; ++nt)
            #pragma unroll
            for (int reg = 0; reg < 4; ++reg) rm = fmaxf(rm, sacc[nt][reg]);
        rm = fmaxf(rm, __shfl_xor(rm, 16));
        rm = fmaxf(rm, __shfl_xor(rm, 32));
        float mn = fmaxf(m_, rm);
        float alpha = exp2f((m_ - mn) * L2E);
        float mnl = mn * L2E;
        float rs = 0.f;
        #pragma unroll
        for (int nt = 0; nt < 4; ++nt) {
            float p0 = exp2f(fmaf(sacc[nt][0], L2E, -mnl));
            float p1 = exp2f(fmaf(sacc[nt][1], L2E, -mnl));
            float p2 = exp2f(fmaf(sacc[nt][2], L2E, -mnl));
            float p3 = exp2f(fmaf(sacc[nt][3], L2E, -mnl));
            rs += (p0 + p1) + (p2 + p3);
            *(uint2*)&Psh[w * 16 + n15][nt * 16 + quad * 4] =
                make_uint2(pk2(p0, p1), pk2(p2, p3));
        }
        rs += __shfl_xor(rs, 16);
        rs += __shfl_xor(rs, 32);
        l_ = fmaf(l_, alpha, rs);
        m_ = mn;
        #pragma unroll
        for (int reg = 0; reg < 4; ++reg) {
            float ar = __shfl(alpha, quad * 4 + reg);
            oacc[0][reg] *= ar; oacc[1][reg] *= ar;
            oacc[2][reg] *= ar; oacc[3][reg] *= ar;
        }

        // ---- PV: O += P·V ----
        s16x8 afr[2];
        afr[0] = *(const s16x8*)&Psh[w * 16 + n15][quad * 8];
        afr[1] = *(const s16x8*)&Psh[w * 16 + n15][32 + quad * 8];
        const char* Vc = (const char*)Vsh;
        #pragma unroll
        for (int nt = 0; nt < 4; ++nt) {
            s16x8 v0 = *(const s16x8*)(Vc + nt * 2048 + off16[0]);
            s16x8 v1 = *(const s16x8*)(Vc + nt * 2048 + off16[1]);
            oacc[nt] = __builtin_amdgcn_mfma_f32_16x16x32_bf16(afr[0], v0, oacc[nt], 0, 0, 0);
            oacc[nt] = __builtin_amdgcn_mfma_f32_16x16x32_bf16(afr[1], v1, oacc[nt], 0, 0, 0);
        }
        __syncthreads();
    }

    // ---- epilogue ----
    if (nsplit == 1) {
        #pragma unroll
        for (int reg = 0; reg < 4; ++reg) {
            float lr = __shfl(l_, quad * 4 + reg);
            float inv = 1.f / fmaxf(lr, 1e-30f);
            int t = t0 + w * 16 + quad * 4 + reg;
            if (t < T) {
                #pragma unroll
                for (int nt = 0; nt < 4; ++nt)
                    out[((size_t)t * HEADS + h) * DH + nt * 16 + n15] = oacc[nt][reg] * inv;
            }
        }
    } else {
        #pragma unroll
        for (int reg = 0; reg < 4; ++reg) {
            int t = t0 + w * 16 + quad * 4 + reg;
            if (t < T) {
                size_t base = (((size_t)split * T + t) * HEADS + h) * DH;
                #pragma unroll
                for (int nt = 0; nt < 4; ++nt)
                    Opart[base + nt * 16 + n15] = oacc[nt][reg];
            }
        }
        int tq = t0 + w * 16 + n15;
        if (quad == 0 && tq < T) {
            size_t mi = ((size_t)split * T + tq) * HEADS + h;
            Mp[mi] = m_; Lp[mi] = l_;
        }
    }
}

// ---------------- split-K combine ----------------
__global__ __launch_bounds__(256)
void fa_combine_kernel(const float* __restrict__ Opart, const float* __restrict__ Mp,
                       const float* __restrict__ Lp, float* __restrict__ out, int T) {
    int i4 = blockIdx.x * blockDim.x + threadIdx.x;
    int total = T * HEADS * (DH / 4);
    if (i4 >= total) return;
    int th = i4 / (DH / 4);
    int d4 = i4 - th * (DH / 4);
    size_t stride = (size_t)T * HEADS * DH;
    int mlstride = T * HEADS;
    float m0 = Mp[th], m1 = Mp[mlstride + th];
    float l0 = Lp[th], l1 = Lp[mlstride + th];
    float M = fmaxf(m0, m1);
    float w0 = exp2f((m0 - M) * L2E);
    float w1 = exp2f((m1 - M) * L2E);
    float L = fmaxf(fmaf(l0, w0, l1 * w1), 1e-30f);
    float inv = 1.f / L;
    size_t off = (size_t)th * DH + 4 * d4;
    float4 a = *(const float4*)&Opart[off];
    float4 b = *(const float4*)&Opart[stride + off];
    float4 o;
    o.x = fmaf(a.x, w0, b.x * w1) * inv;
    o.y = fmaf(a.y, w0, b.y * w1) * inv;
    o.z = fmaf(a.z, w0, b.z * w1) * inv;
    o.w = fmaf(a.w, w0, b.w * w1) * inv;
    *(float4*)&out[off] = o;
}

extern "C" void kernel_launch(void* const* d_in, const int* in_sizes, int n_in,
                              void* d_out, int out_size, void* d_ws, size_t ws_size,
                              hipStream_t stream) {
    const float* qkv = (const float*)d_in[0];
    const int* cu    = (const int*)d_in[1];
    const int n_cu   = in_sizes[1];
    const int T      = in_sizes[0] / (3 * HEADS * DH);
    float* out       = (float*)d_out;

    const int NSPLIT = 2;
    size_t elems = (size_t)T * HEADS * DH;

    float* Opart = (float*)d_ws;                                  // NSPLIT*elems f32
    float* Mpp   = Opart + (size_t)NSPLIT * elems;                // NSPLIT*T*H f32
    float* Lpp   = Mpp + (size_t)NSPLIT * T * HEADS;
    unsigned short* Qb  = (unsigned short*)(Lpp + (size_t)NSPLIT * T * HEADS);
    unsigned short* Kb  = Qb + elems;
    unsigned short* Vtb = Kb + elems;

    int tiles = (T + TQ - 1) / TQ;
    dim3 pgrid(tiles, HEADS, 3);
    prep_kernel<<<pgrid, 256, 0, stream>>>(qkv, Qb, Kb, Vtb, T);

    dim3 grid(tiles, HEADS, NSPLIT);
    fa_main<<<grid, 256, 0, stream>>>(Qb, Kb, Vtb, cu, n_cu, T, out, Opart, Mpp, Lpp);

    int total4 = T * HEADS * (DH / 4);
    fa_combine_kernel<<<(total4 + 255) / 256, 256, 0, stream>>>(Opart, Mpp, Lpp, out, T);
}